// Round 2
// baseline (1783.231 us; speedup 1.0000x reference)
//
#include <hip/hip_runtime.h>
#include <hip/hip_bf16.h>

#define BB 4
#define CPc 256
#define PL 64
#define NN 2304   // 48*48

// ---------------- K1: tq[b][n][c] = sum_k t_w[c][k] * persp[b][k][n] ----------------
// grid = BB * (NN/4), block = 256 (64 c x 4 n)
__global__ __launch_bounds__(256) void k_tq(const float* __restrict__ persp,
                                            const float* __restrict__ t_w,
                                            float* __restrict__ tq) {
    __shared__ float s_tw[64][65];
    __shared__ float s_px[64][4];
    int t = threadIdx.x;
    int b = blockIdx.x / (NN / 4);
    int n0 = (blockIdx.x % (NN / 4)) * 4;
    int c = t & 63, nn = t >> 6;
    float acc = 0.f;
    for (int kc = 0; kc < 256; kc += 64) {
#pragma unroll
        for (int r = 0; r < 16; ++r) {
            int e = t + r * 256;
            int cl = e >> 6, kl = e & 63;
            s_tw[cl][kl] = t_w[cl * 256 + kc + kl];
        }
        {
            int kl = t >> 2, n2 = t & 3;
            s_px[kl][n2] = persp[(b * CPc + kc + kl) * NN + n0 + n2];
        }
        __syncthreads();
#pragma unroll 16
        for (int kk = 0; kk < 64; ++kk)
            acc += s_tw[c][kk] * s_px[kk][nn];
        __syncthreads();
    }
    tq[(b * NN + n0 + nn) * 64 + c] = acc;
}

// ---------------- K2: pT[b][m][c], gT[b][m][c] from resp ----------------
// grid = BB * (M/4), block = 256 (64 c x 4 m)
__global__ __launch_bounds__(256) void k_pg(const float* __restrict__ resp,
                                            const float* __restrict__ p_w,
                                            const float* __restrict__ g_w,
                                            float* __restrict__ pT, float* __restrict__ gT,
                                            int Cr, int M) {
    __shared__ float s_pw[64][65];
    __shared__ float s_gw[64][65];
    __shared__ float s_r[64][4];
    int t = threadIdx.x;
    int mb = M >> 2;
    int b = blockIdx.x / mb;
    int m0 = (blockIdx.x % mb) * 4;
    int c = t & 63, mm = t >> 6;
    float accP = 0.f, accG = 0.f;
    for (int kc = 0; kc < Cr; kc += 64) {
#pragma unroll
        for (int r = 0; r < 16; ++r) {
            int e = t + r * 256;
            int cl = e >> 6, kl = e & 63;
            s_pw[cl][kl] = p_w[cl * Cr + kc + kl];
            s_gw[cl][kl] = g_w[cl * Cr + kc + kl];
        }
        {
            int kl = t >> 2, m2 = t & 3;
            s_r[kl][m2] = resp[(b * Cr + kc + kl) * M + m0 + m2];
        }
        __syncthreads();
#pragma unroll 16
        for (int kk = 0; kk < 64; ++kk) {
            float rv = s_r[kk][mm];
            accP += s_pw[c][kk] * rv;
            accG += s_gw[c][kk] * rv;
        }
        __syncthreads();
    }
    pT[(b * M + m0 + mm) * 64 + c] = accP;
    gT[(b * M + m0 + mm) * 64 + c] = accG;
}

// ---------------- K3: flash attention, 16 q-rows per block ----------------
// out_mat[b][n][c] = softmax_m(tq[b][n][:] . pT[b][m][:]) @ gT[b][m][c]
// grid = BB * (NN/16), block = 256
__global__ __launch_bounds__(256) void k_attn(const float* __restrict__ tq,
                                              const float* __restrict__ pT,
                                              const float* __restrict__ gT,
                                              float* __restrict__ outm, int M) {
    __shared__ float s_tq[16][65];
    __shared__ float s_p[64][65];
    __shared__ float s_g[64][65];
    __shared__ float s_sc[16][65];
    __shared__ float s_m[16], s_l[16], s_al[16];
    int t = threadIdx.x;
    int b = blockIdx.x / (NN / 16);
    int n0 = (blockIdx.x % (NN / 16)) * 16;
    {
        int rr = t >> 6, cc = t & 63;
#pragma unroll
        for (int r = 0; r < 4; ++r)
            s_tq[r * 4 + rr][cc] = tq[(b * NN + n0 + r * 4 + rr) * 64 + cc];
    }
    if (t < 16) { s_m[t] = -1e30f; s_l[t] = 0.f; }
    __syncthreads();
    int c = t & 63, rg = t >> 6;   // c doubles as mm in score phase; rg uniform per wave
    float accO[4] = {0.f, 0.f, 0.f, 0.f};
    for (int m0 = 0; m0 < M; m0 += 64) {
        // stage K/V chunk
#pragma unroll
        for (int r = 0; r < 16; ++r) {
            int e = t + r * 256;
            int ml = e >> 6, cl = e & 63;
            int gm = m0 + ml;
            float pv = 0.f, gv = 0.f;
            if (gm < M) {
                pv = pT[(b * M + gm) * 64 + cl];
                gv = gT[(b * M + gm) * 64 + cl];
            }
            s_p[ml][cl] = pv;
            s_g[ml][cl] = gv;
        }
        __syncthreads();
        // scores: thread (mm=c, rg) -> rows rg*4+rr, column mm
        float sc[4] = {0.f, 0.f, 0.f, 0.f};
        bool valid = (m0 + c) < M;
        for (int cc = 0; cc < 64; ++cc) {
            float pv = s_p[c][cc];
#pragma unroll
            for (int rr = 0; rr < 4; ++rr)
                sc[rr] += pv * s_tq[rg * 4 + rr][cc];
        }
#pragma unroll
        for (int rr = 0; rr < 4; ++rr)
            s_sc[rg * 4 + rr][c] = valid ? sc[rr] : -1e30f;
        __syncthreads();
        // online softmax: 16 groups of 16 threads, group gid owns row gid
        {
            int gid = t >> 4, lid = t & 15;
            float v0 = s_sc[gid][lid], v1 = s_sc[gid][lid + 16];
            float v2 = s_sc[gid][lid + 32], v3 = s_sc[gid][lid + 48];
            float mx = fmaxf(fmaxf(v0, v1), fmaxf(v2, v3));
            for (int o = 8; o >= 1; o >>= 1)
                mx = fmaxf(mx, __shfl_xor(mx, o, 16));
            float om = s_m[gid];
            float nm = fmaxf(om, mx);
            float e0 = __expf(v0 - nm), e1 = __expf(v1 - nm);
            float e2 = __expf(v2 - nm), e3 = __expf(v3 - nm);
            float ps = e0 + e1 + e2 + e3;
            for (int o = 8; o >= 1; o >>= 1)
                ps += __shfl_xor(ps, o, 16);
            s_sc[gid][lid] = e0; s_sc[gid][lid + 16] = e1;
            s_sc[gid][lid + 32] = e2; s_sc[gid][lid + 48] = e3;
            if (lid == 0) {
                float al = __expf(om - nm);
                s_al[gid] = al;
                s_m[gid] = nm;
                s_l[gid] = s_l[gid] * al + ps;
            }
        }
        __syncthreads();
        // AV: thread (c, rg) accumulates rows rg*4+rr at column c
#pragma unroll
        for (int rr = 0; rr < 4; ++rr)
            accO[rr] *= s_al[rg * 4 + rr];
        for (int k = 0; k < 64; ++k) {
            float gv = s_g[k][c];
#pragma unroll
            for (int rr = 0; rr < 4; ++rr)
                accO[rr] += s_sc[rg * 4 + rr][k] * gv;
        }
        __syncthreads();
    }
#pragma unroll
    for (int rr = 0; rr < 4; ++rr) {
        int row = rg * 4 + rr;
        outm[(b * NN + n0 + row) * 64 + c] = accO[rr] / s_l[row];
    }
}

// ---------------- K4: z[b][q][j*64+l] = sum_cp z_w[q][cp] * outm[b][cp*36+j][l] ----------------
// (faithful "wrong reshape": view[b][cp][j*64+l] = outm[b][cp*36+j][l], 2304 = 36*64)
// grid = BB * 36 * 4 (q-chunks of 64), block = 256 (64 l x 4 qg)
__global__ __launch_bounds__(256) void k_z(const float* __restrict__ outm,
                                           const float* __restrict__ z_w,
                                           float* __restrict__ z) {
    __shared__ float s_u[64][65];
    __shared__ float s_zw[64][65];
    int t = threadIdx.x;
    int blk = blockIdx.x;
    int b = blk / (36 * 4);
    int rem = blk % (36 * 4);
    int j = rem / 4;
    int qc = (rem % 4) * 64;
#pragma unroll
    for (int r = 0; r < 16; ++r) {
        int e = t + r * 256;
        int cl = e >> 6, ll = e & 63;
        s_u[cl][ll] = outm[(b * NN + cl * 36 + j) * 64 + ll];
        s_zw[cl][ll] = z_w[(qc + cl) * 64 + ll];
    }
    __syncthreads();
    int l = t & 63, qg = t >> 6;   // qg uniform per wave
    float acc[16];
#pragma unroll
    for (int i = 0; i < 16; ++i) acc[i] = 0.f;
    for (int cc = 0; cc < 64; ++cc) {
        float uv = s_u[cc][l];
#pragma unroll
        for (int qq = 0; qq < 16; ++qq)
            acc[qq] += s_zw[qg * 16 + qq][cc] * uv;
    }
#pragma unroll
    for (int qq = 0; qq < 16; ++qq)
        z[(b * CPc + qc + qg * 16 + qq) * NN + j * 64 + l] = acc[qq];
}

// ---------------- K5: per-channel sum / sumsq (1 block per q, deterministic) ----------------
__global__ __launch_bounds__(256) void k_stats(const float* __restrict__ z,
                                               float* __restrict__ stats) {
    int q = blockIdx.x;
    int t = threadIdx.x;
    float s = 0.f, s2 = 0.f;
    for (int i = t; i < BB * NN; i += 256) {
        int b = i / NN, sp = i % NN;
        float v = z[(b * CPc + q) * NN + sp];
        s += v; s2 += v * v;
    }
    for (int o = 32; o >= 1; o >>= 1) {
        s += __shfl_down(s, o, 64);
        s2 += __shfl_down(s2, o, 64);
    }
    __shared__ float sh[2][4];
    int w = t >> 6, lane = t & 63;
    if (lane == 0) { sh[0][w] = s; sh[1][w] = s2; }
    __syncthreads();
    if (t == 0) {
        stats[q * 2]     = sh[0][0] + sh[0][1] + sh[0][2] + sh[0][3];
        stats[q * 2 + 1] = sh[1][0] + sh[1][1] + sh[1][2] + sh[1][3];
    }
}

// ---------------- K6: BN normalize + accumulate (mode 0 write / 1 add / 2 add+final) --------
__global__ __launch_bounds__(256) void k_norm(const float* __restrict__ z,
                                              const float* __restrict__ stats,
                                              const float* __restrict__ gamma,
                                              const float* __restrict__ beta,
                                              float* __restrict__ acc,
                                              float* __restrict__ outp,
                                              int mode) {
    int idx = blockIdx.x * 256 + threadIdx.x;
    if (idx >= BB * CPc * NN) return;
    int q = (idx / NN) & 255;
    float inv = 1.f / (float)(BB * NN);
    float mean = stats[q * 2] * inv;
    float var = stats[q * 2 + 1] * inv - mean * mean;
    float r = rsqrtf(var + 1e-5f);
    float v = (z[idx] - mean) * r * gamma[q] + beta[q];
    if (mode == 0)      acc[idx] = v;
    else if (mode == 1) acc[idx] += v;
    else                outp[idx] = acc[idx] + v;
}

extern "C" void kernel_launch(void* const* d_in, const int* in_sizes, int n_in,
                              void* d_out, int out_size, void* d_ws, size_t ws_size,
                              hipStream_t stream) {
    const float* persp = (const float*)d_in[0];
    const float* resp[5];
    for (int i = 0; i < 5; ++i) resp[i] = (const float*)d_in[1 + i];
    const float* t_w = (const float*)d_in[6];
    const float* z_w = (const float*)d_in[7];
    const float *p_w[5], *g_w[5], *bng[5], *bnb[5];
    for (int i = 0; i < 5; ++i) {
        p_w[i] = (const float*)d_in[8 + 4 * i];
        g_w[i] = (const float*)d_in[9 + 4 * i];
        bng[i] = (const float*)d_in[10 + 4 * i];
        bnb[i] = (const float*)d_in[11 + 4 * i];
    }
    float* ws = (float*)d_ws;
    float* TQ = ws;                    // 4*2304*64   = 589824
    float* PT = TQ + 589824;
    float* GT = PT + 589824;
    float* OUT = GT + 589824;
    float* Z = OUT + 589824;           // 4*256*2304  = 2359296
    float* ACC = Z + 2359296;
    float* STATS = ACC + 2359296;      // 512

    const int Ms[5]  = {2304, 2304, 576, 144, 36};
    const int Crs[5] = {64, 256, 512, 1024, 2048};

    k_tq<<<BB * (NN / 4), 256, 0, stream>>>(persp, t_w, TQ);
    for (int i = 0; i < 5; ++i) {
        int M = Ms[i], Cr = Crs[i];
        k_pg<<<BB * (M / 4), 256, 0, stream>>>(resp[i], p_w[i], g_w[i], PT, GT, Cr, M);
        k_attn<<<BB * (NN / 16), 256, 0, stream>>>(TQ, PT, GT, OUT, M);
        k_z<<<BB * 36 * 4, 256, 0, stream>>>(OUT, z_w, Z);
        k_stats<<<256, 256, 0, stream>>>(Z, STATS);
        int mode = (i == 0) ? 0 : ((i == 4) ? 2 : 1);
        k_norm<<<BB * CPc * NN / 256, 256, 0, stream>>>(Z, STATS, bng[i], bnb[i], ACC,
                                                        (float*)d_out, mode);
    }
}

// Round 3
// 770.644 us; speedup vs baseline: 2.3139x; 2.3139x over previous
//
#include <hip/hip_runtime.h>
#include <hip/hip_bf16.h>

#define BB 4
#define CPc 256
#define NN 2304   // 48*48

typedef __attribute__((ext_vector_type(8))) short bf16x8;
typedef __attribute__((ext_vector_type(4))) float f32x4;

__device__ __forceinline__ short f2b(float x) {
    __hip_bfloat16 h = __float2bfloat16(x);
    return *reinterpret_cast<short*>(&h);
}

// ---------------- K1: tq[b][n][c] = sum_k t_w[c][k] * persp[b][k][n] ----------------
// grid = BB * (NN/4), block = 256 (64 c x 4 n)
__global__ __launch_bounds__(256) void k_tq(const float* __restrict__ persp,
                                            const float* __restrict__ t_w,
                                            float* __restrict__ tq) {
    __shared__ float s_tw[64][65];
    __shared__ float s_px[64][4];
    int t = threadIdx.x;
    int b = blockIdx.x / (NN / 4);
    int n0 = (blockIdx.x % (NN / 4)) * 4;
    int c = t & 63, nn = t >> 6;
    float acc = 0.f;
    for (int kc = 0; kc < 256; kc += 64) {
#pragma unroll
        for (int r = 0; r < 16; ++r) {
            int e = t + r * 256;
            int cl = e >> 6, kl = e & 63;
            s_tw[cl][kl] = t_w[cl * 256 + kc + kl];
        }
        {
            int kl = t >> 2, n2 = t & 3;
            s_px[kl][n2] = persp[(b * CPc + kc + kl) * NN + n0 + n2];
        }
        __syncthreads();
#pragma unroll 16
        for (int kk = 0; kk < 64; ++kk)
            acc += s_tw[c][kk] * s_px[kk][nn];
        __syncthreads();
    }
    tq[(b * NN + n0 + nn) * 64 + c] = acc;
}

// ---------------- K2: pT[b][m][c] and gTt[b][c][m] from resp ----------------
// grid = BB * (M/4), block = 256 (64 c x 4 m)
__global__ __launch_bounds__(256) void k_pg(const float* __restrict__ resp,
                                            const float* __restrict__ p_w,
                                            const float* __restrict__ g_w,
                                            float* __restrict__ pT, float* __restrict__ gTt,
                                            int Cr, int M) {
    __shared__ float s_pw[64][65];
    __shared__ float s_gw[64][65];
    __shared__ float s_r[64][4];
    int t = threadIdx.x;
    int mb = M >> 2;
    int b = blockIdx.x / mb;
    int m0 = (blockIdx.x % mb) * 4;
    int c = t & 63, mm = t >> 6;
    float accP = 0.f, accG = 0.f;
    for (int kc = 0; kc < Cr; kc += 64) {
#pragma unroll
        for (int r = 0; r < 16; ++r) {
            int e = t + r * 256;
            int cl = e >> 6, kl = e & 63;
            s_pw[cl][kl] = p_w[cl * Cr + kc + kl];
            s_gw[cl][kl] = g_w[cl * Cr + kc + kl];
        }
        {
            int kl = t >> 2, m2 = t & 3;
            s_r[kl][m2] = resp[(b * Cr + kc + kl) * M + m0 + m2];
        }
        __syncthreads();
#pragma unroll 16
        for (int kk = 0; kk < 64; ++kk) {
            float rv = s_r[kk][mm];
            accP += s_pw[c][kk] * rv;
            accG += s_gw[c][kk] * rv;
        }
        __syncthreads();
    }
    pT[((size_t)b * M + m0 + mm) * 64 + c] = accP;
    gTt[((size_t)b * 64 + c) * M + m0 + mm] = accG;   // transposed copy for MFMA B-operand
}

// ---------------- K3: MFMA flash attention, 16 q-rows per block ----------------
// outm[b][n][c] = softmax_m(tq[b][n][:] . p[b][m][:]) @ g[b][m][c]
// grid = BB * (NN/16), block = 256 (4 waves; wave w = m-tile (QK) / c-tile (AV))
__global__ __launch_bounds__(256) void k_attn(const float* __restrict__ tq,
                                              const float* __restrict__ pT,
                                              const float* __restrict__ gTt,
                                              float* __restrict__ outm, int M) {
    __shared__ __align__(16) short s_tq[16][72];  // [n][d] bf16, pad->2-way free
    __shared__ __align__(16) short s_p [64][72];  // [m][d] bf16
    __shared__ __align__(16) short s_gt[64][72];  // [c][m] bf16
    __shared__ __align__(16) short s_P [16][72];  // [n][m] bf16 (exp'd scores)
    __shared__ float s_red [4][16];
    __shared__ float s_red2[4][16];
    __shared__ float s_alpha[16];
    __shared__ float s_lf[16];

    int t = threadIdx.x;
    int b = blockIdx.x / (NN / 16);
    int n0 = (blockIdx.x % (NN / 16)) * 16;
    int w = t >> 6;
    int lane = t & 63;
    int lo = lane & 15;
    int quad = lane >> 4;

    // stage q-tile once: 16 rows x 16 float4
    {
        int n = t >> 4, c4 = (t & 15) * 4;
        const float4 v = *(const float4*)&tq[((size_t)b * NN + n0 + n) * 64 + c4];
        short4 pk; pk.x = f2b(v.x); pk.y = f2b(v.y); pk.z = f2b(v.z); pk.w = f2b(v.w);
        *(short4*)&s_tq[n][c4] = pk;
    }

    f32x4 accO = {0.f, 0.f, 0.f, 0.f};
    float m_run = -1e30f, l_run = 0.f;
    int nch = (M + 63) >> 6;
    for (int ch = 0; ch < nch; ++ch) {
        int m0 = ch << 6;
        __syncthreads();   // protect s_p/s_gt/s_P readers of previous chunk
        // stage K (s_p[m][d]) and V^T (s_gt[c][m]); 64x16 float4 each, 4/thread
#pragma unroll
        for (int r = 0; r < 4; ++r) {
            int idx = t + r * 256;
            int row = idx >> 4, e4 = (idx & 15) * 4;
            float4 v = {0.f, 0.f, 0.f, 0.f};
            if (m0 + row < M)
                v = *(const float4*)&pT[((size_t)b * M + m0 + row) * 64 + e4];
            short4 pk; pk.x = f2b(v.x); pk.y = f2b(v.y); pk.z = f2b(v.z); pk.w = f2b(v.w);
            *(short4*)&s_p[row][e4] = pk;
            float4 g = {0.f, 0.f, 0.f, 0.f};
            if (m0 + e4 < M)        // all M are multiples of 4
                g = *(const float4*)&gTt[((size_t)b * 64 + row) * M + m0 + e4];
            short4 gk; gk.x = f2b(g.x); gk.y = f2b(g.y); gk.z = f2b(g.z); gk.w = f2b(g.w);
            *(short4*)&s_gt[row][e4] = gk;
        }
        __syncthreads();
        // QK: S[m][n], wave w owns m-tile w. A = s_p rows, B = s_tq rows (as B^T).
        f32x4 S = {0.f, 0.f, 0.f, 0.f};
        {
            const bf16x8 a0 = *(const bf16x8*)&s_p[w * 16 + lo][quad * 8];
            const bf16x8 b0 = *(const bf16x8*)&s_tq[lo][quad * 8];
            S = __builtin_amdgcn_mfma_f32_16x16x32_bf16(a0, b0, S, 0, 0, 0);
            const bf16x8 a1 = *(const bf16x8*)&s_p[w * 16 + lo][32 + quad * 8];
            const bf16x8 b1 = *(const bf16x8*)&s_tq[lo][32 + quad * 8];
            S = __builtin_amdgcn_mfma_f32_16x16x32_bf16(a1, b1, S, 0, 0, 0);
        }
        // mask tail + chunk max per column n=lo (rows m = quad*4+reg within tile)
        float cmax = -1e30f;
#pragma unroll
        for (int rg = 0; rg < 4; ++rg) {
            int mglob = m0 + w * 16 + quad * 4 + rg;
            if (mglob >= M) S[rg] = -1e30f;
            cmax = fmaxf(cmax, S[rg]);
        }
        cmax = fmaxf(cmax, __shfl_xor(cmax, 16, 64));
        cmax = fmaxf(cmax, __shfl_xor(cmax, 32, 64));
        if (lane < 16) s_red[w][lo] = cmax;
        __syncthreads();
        float chmax = fmaxf(fmaxf(s_red[0][lo], s_red[1][lo]),
                            fmaxf(s_red[2][lo], s_red[3][lo]));
        float m_new = fmaxf(m_run, chmax);
        float alpha = __expf(m_run - m_new);
        float psum = 0.f;
        short4 pw;
#pragma unroll
        for (int rg = 0; rg < 4; ++rg) {
            float e = __expf(S[rg] - m_new);
            psum += e;
            ((short*)&pw)[rg] = f2b(e);
        }
        psum += __shfl_xor(psum, 16, 64);
        psum += __shfl_xor(psum, 32, 64);
        if (lane < 16) s_red2[w][lo] = psum;
        if (t < 16) s_alpha[t] = alpha;                   // identical across threads per lo
        *(short4*)&s_P[lo][w * 16 + quad * 4] = pw;       // P'[n][m], packed 4 m per lane
        __syncthreads();
        l_run = l_run * alpha +
                (s_red2[0][lo] + s_red2[1][lo] + s_red2[2][lo] + s_red2[3][lo]);
        m_run = m_new;
        // AV: O[n][c], wave w owns c-tile w; rescale rows n = quad*4+reg first
#pragma unroll
        for (int rg = 0; rg < 4; ++rg)
            accO[rg] *= s_alpha[quad * 4 + rg];
        {
            const bf16x8 a0 = *(const bf16x8*)&s_P[lo][quad * 8];
            const bf16x8 b0 = *(const bf16x8*)&s_gt[w * 16 + lo][quad * 8];
            accO = __builtin_amdgcn_mfma_f32_16x16x32_bf16(a0, b0, accO, 0, 0, 0);
            const bf16x8 a1 = *(const bf16x8*)&s_P[lo][32 + quad * 8];
            const bf16x8 b1 = *(const bf16x8*)&s_gt[w * 16 + lo][32 + quad * 8];
            accO = __builtin_amdgcn_mfma_f32_16x16x32_bf16(a1, b1, accO, 0, 0, 0);
        }
    }
    __syncthreads();
    if (t < 16) s_lf[t] = l_run;
    __syncthreads();
#pragma unroll
    for (int rg = 0; rg < 4; ++rg) {
        int n = quad * 4 + rg;
        outm[((size_t)b * NN + n0 + n) * 64 + w * 16 + lo] = accO[rg] / s_lf[n];
    }
}

// ---------------- K4: z[b][q][j*64+l] = sum_cp z_w[q][cp] * outm[b][cp*36+j][l] ----------------
// (faithful "wrong reshape": view[b][cp][j*64+l] = outm[b][cp*36+j][l], 2304 = 36*64)
__global__ __launch_bounds__(256) void k_z(const float* __restrict__ outm,
                                           const float* __restrict__ z_w,
                                           float* __restrict__ z) {
    __shared__ float s_u[64][65];
    __shared__ float s_zw[64][65];
    int t = threadIdx.x;
    int blk = blockIdx.x;
    int b = blk / (36 * 4);
    int rem = blk % (36 * 4);
    int j = rem / 4;
    int qc = (rem % 4) * 64;
#pragma unroll
    for (int r = 0; r < 16; ++r) {
        int e = t + r * 256;
        int cl = e >> 6, ll = e & 63;
        s_u[cl][ll] = outm[(b * NN + cl * 36 + j) * 64 + ll];
        s_zw[cl][ll] = z_w[(qc + cl) * 64 + ll];
    }
    __syncthreads();
    int l = t & 63, qg = t >> 6;
    float acc[16];
#pragma unroll
    for (int i = 0; i < 16; ++i) acc[i] = 0.f;
    for (int cc = 0; cc < 64; ++cc) {
        float uv = s_u[cc][l];
#pragma unroll
        for (int qq = 0; qq < 16; ++qq)
            acc[qq] += s_zw[qg * 16 + qq][cc] * uv;
    }
#pragma unroll
    for (int qq = 0; qq < 16; ++qq)
        z[(b * CPc + qc + qg * 16 + qq) * NN + j * 64 + l] = acc[qq];
}

// ---------------- K5: per-channel sum / sumsq ----------------
__global__ __launch_bounds__(256) void k_stats(const float* __restrict__ z,
                                               float* __restrict__ stats) {
    int q = blockIdx.x;
    int t = threadIdx.x;
    float s = 0.f, s2 = 0.f;
    for (int i = t; i < BB * NN; i += 256) {
        int b = i / NN, sp = i % NN;
        float v = z[(b * CPc + q) * NN + sp];
        s += v; s2 += v * v;
    }
    for (int o = 32; o >= 1; o >>= 1) {
        s += __shfl_down(s, o, 64);
        s2 += __shfl_down(s2, o, 64);
    }
    __shared__ float sh[2][4];
    int w = t >> 6, lane = t & 63;
    if (lane == 0) { sh[0][w] = s; sh[1][w] = s2; }
    __syncthreads();
    if (t == 0) {
        stats[q * 2]     = sh[0][0] + sh[0][1] + sh[0][2] + sh[0][3];
        stats[q * 2 + 1] = sh[1][0] + sh[1][1] + sh[1][2] + sh[1][3];
    }
}

// ---------------- K6: BN normalize + accumulate ----------------
__global__ __launch_bounds__(256) void k_norm(const float* __restrict__ z,
                                              const float* __restrict__ stats,
                                              const float* __restrict__ gamma,
                                              const float* __restrict__ beta,
                                              float* __restrict__ acc,
                                              float* __restrict__ outp,
                                              int mode) {
    int idx = blockIdx.x * 256 + threadIdx.x;
    if (idx >= BB * CPc * NN) return;
    int q = (idx / NN) & 255;
    float inv = 1.f / (float)(BB * NN);
    float mean = stats[q * 2] * inv;
    float var = stats[q * 2 + 1] * inv - mean * mean;
    float r = rsqrtf(var + 1e-5f);
    float v = (z[idx] - mean) * r * gamma[q] + beta[q];
    if (mode == 0)      acc[idx] = v;
    else if (mode == 1) acc[idx] += v;
    else                outp[idx] = acc[idx] + v;
}

extern "C" void kernel_launch(void* const* d_in, const int* in_sizes, int n_in,
                              void* d_out, int out_size, void* d_ws, size_t ws_size,
                              hipStream_t stream) {
    const float* persp = (const float*)d_in[0];
    const float* resp[5];
    for (int i = 0; i < 5; ++i) resp[i] = (const float*)d_in[1 + i];
    const float* t_w = (const float*)d_in[6];
    const float* z_w = (const float*)d_in[7];
    const float *p_w[5], *g_w[5], *bng[5], *bnb[5];
    for (int i = 0; i < 5; ++i) {
        p_w[i] = (const float*)d_in[8 + 4 * i];
        g_w[i] = (const float*)d_in[9 + 4 * i];
        bng[i] = (const float*)d_in[10 + 4 * i];
        bnb[i] = (const float*)d_in[11 + 4 * i];
    }
    float* ws = (float*)d_ws;
    float* TQ  = ws;                    // 4*2304*64 = 589824
    float* PT  = TQ + 589824;
    float* GTT = PT + 589824;           // transposed g: [b][c][M]
    float* OUT = GTT + 589824;
    float* Z   = OUT + 589824;          // 4*256*2304 = 2359296
    float* ACC = Z + 2359296;
    float* STATS = ACC + 2359296;       // 512

    const int Ms[5]  = {2304, 2304, 576, 144, 36};
    const int Crs[5] = {64, 256, 512, 1024, 2048};

    k_tq<<<BB * (NN / 4), 256, 0, stream>>>(persp, t_w, TQ);
    for (int i = 0; i < 5; ++i) {
        int M = Ms[i], Cr = Crs[i];
        k_pg<<<BB * (M / 4), 256, 0, stream>>>(resp[i], p_w[i], g_w[i], PT, GTT, Cr, M);
        k_attn<<<BB * (NN / 16), 256, 0, stream>>>(TQ, PT, GTT, OUT, M);
        k_z<<<BB * 36 * 4, 256, 0, stream>>>(OUT, z_w, Z);
        k_stats<<<256, 256, 0, stream>>>(Z, STATS);
        int mode = (i == 0) ? 0 : ((i == 4) ? 2 : 1);
        k_norm<<<BB * CPc * NN / 256, 256, 0, stream>>>(Z, STATS, bng[i], bnb[i], ACC,
                                                        (float*)d_out, mode);
    }
}

// Round 4
// 595.544 us; speedup vs baseline: 2.9943x; 1.2940x over previous
//
#include <hip/hip_runtime.h>
#include <hip/hip_bf16.h>

#define BB 4
#define CPc 256
#define NN 2304   // 48*48

typedef __attribute__((ext_vector_type(8))) short bf16x8;
typedef __attribute__((ext_vector_type(4))) float f32x4;

__device__ __forceinline__ short f2b(float x) {
    __hip_bfloat16 h = __float2bfloat16(x);
    return *reinterpret_cast<short*>(&h);
}

// ---------------- K1: tq[b][n][c] = sum_k t_w[c][k] * persp[b][k][n]  (bf16 out) ----------
// grid = BB * (NN/4), block = 256 (64 c x 4 n)
__global__ __launch_bounds__(256) void k_tq(const float* __restrict__ persp,
                                            const float* __restrict__ t_w,
                                            short* __restrict__ tq) {
    __shared__ float s_tw[64][65];
    __shared__ float s_px[64][4];
    int t = threadIdx.x;
    int b = blockIdx.x / (NN / 4);
    int n0 = (blockIdx.x % (NN / 4)) * 4;
    int c = t & 63, nn = t >> 6;
    float acc = 0.f;
    for (int kc = 0; kc < 256; kc += 64) {
#pragma unroll
        for (int r = 0; r < 16; ++r) {
            int e = t + r * 256;
            int cl = e >> 6, kl = e & 63;
            s_tw[cl][kl] = t_w[cl * 256 + kc + kl];
        }
        {
            int kl = t >> 2, n2 = t & 3;
            s_px[kl][n2] = persp[(b * CPc + kc + kl) * NN + n0 + n2];
        }
        __syncthreads();
#pragma unroll 16
        for (int kk = 0; kk < 64; ++kk)
            acc += s_tw[c][kk] * s_px[kk][nn];
        __syncthreads();
    }
    tq[((size_t)b * NN + n0 + nn) * 64 + c] = f2b(acc);
}

// ---------------- K2: p/g 1x1 convs. S==1: bf16 pT[b][m][c] + gTt[b][c][m] direct.
//                  S>1 : fp32 partials (split over Cr), reduced by k_conv. ----------------
// grid = BB * (M/4) * S, block = 256 (64 c x 4 m)
__global__ __launch_bounds__(256) void k_pg(const float* __restrict__ resp,
                                            const float* __restrict__ p_w,
                                            const float* __restrict__ g_w,
                                            short* __restrict__ pTb, short* __restrict__ gTb,
                                            float* __restrict__ Ppart, float* __restrict__ Gpart,
                                            int Cr, int M, int Mp, int S) {
    __shared__ float s_pw[64][65];
    __shared__ float s_gw[64][65];
    __shared__ float s_r[64][4];
    int t = threadIdx.x;
    int mb = M >> 2;
    int blk = blockIdx.x;
    int s = blk % S;
    int rest = blk / S;
    int b = rest / mb;
    int m0 = (rest % mb) * 4;
    int c = t & 63, mm = t >> 6;
    int kLen = Cr / S, k0 = s * kLen;
    float accP = 0.f, accG = 0.f;
    for (int kc = k0; kc < k0 + kLen; kc += 64) {
#pragma unroll
        for (int r = 0; r < 16; ++r) {
            int e = t + r * 256;
            int cl = e >> 6, kl = e & 63;
            s_pw[cl][kl] = p_w[cl * Cr + kc + kl];
            s_gw[cl][kl] = g_w[cl * Cr + kc + kl];
        }
        {
            int kl = t >> 2, m2 = t & 3;
            s_r[kl][m2] = resp[((size_t)b * Cr + kc + kl) * M + m0 + m2];
        }
        __syncthreads();
#pragma unroll 16
        for (int kk = 0; kk < 64; ++kk) {
            float rv = s_r[kk][mm];
            accP += s_pw[c][kk] * rv;
            accG += s_gw[c][kk] * rv;
        }
        __syncthreads();
    }
    if (S == 1) {
        pTb[((size_t)b * Mp + m0 + mm) * 64 + c] = f2b(accP);
        gTb[((size_t)b * 64 + c) * Mp + m0 + mm] = f2b(accG);
    } else {
        size_t idx = (((size_t)s * BB + b) * M + m0 + mm) * 64 + c;
        Ppart[idx] = accP;
        Gpart[idx] = accG;
    }
}

// ---------------- K2b: reduce split partials -> bf16 pT/gTt, zero-pad m in [M, Mp) --------
// grid = BB*Mp*64/256
__global__ __launch_bounds__(256) void k_conv(const float* __restrict__ Ppart,
                                              const float* __restrict__ Gpart,
                                              short* __restrict__ pTb, short* __restrict__ gTb,
                                              int M, int Mp, int S) {
    int idx = blockIdx.x * 256 + threadIdx.x;
    int c = idx & 63;
    int m = (idx >> 6) % Mp;
    int b = idx / (Mp * 64);
    float p = 0.f, g = 0.f;
    if (m < M) {
        for (int s = 0; s < S; ++s) {
            size_t q = (((size_t)s * BB + b) * M + m) * 64 + c;
            p += Ppart[q];
            g += Gpart[q];
        }
    }
    pTb[((size_t)b * Mp + m) * 64 + c] = f2b(p);
    gTb[((size_t)b * 64 + c) * Mp + m] = f2b(g);
}

// ---------------- K3: MFMA flash attention, 32 q-rows/block, direct-global fragments ------
// grid = BB * (NN/32), block = 256 (wave w = m-tile (QK) / c-tile (AV))
__global__ __launch_bounds__(256) void k_attn(const short* __restrict__ tq,
                                              const short* __restrict__ pT,
                                              const short* __restrict__ gT,
                                              float* __restrict__ outm,
                                              int M, int Mp) {
    __shared__ __align__(16) short s_P[32][72];   // P'[n][m] bf16
    __shared__ float s_red[4][32];
    __shared__ float s_red2[4][32];
    __shared__ float s_alpha[32];
    __shared__ float s_lf[32];

    int t = threadIdx.x;
    int b = blockIdx.x / (NN / 32);
    int n0 = (blockIdx.x % (NN / 32)) * 32;
    int w = t >> 6, lane = t & 63, lo = lane & 15, quad = lane >> 4;

    // q-tile in registers: 2 n-tiles x 2 k-halves
    const short* tqB = tq + ((size_t)b * NN + n0 + lo) * 64 + quad * 8;
    bf16x8 bq[2][2];
#pragma unroll
    for (int i = 0; i < 2; ++i)
#pragma unroll
        for (int h = 0; h < 2; ++h)
            bq[i][h] = *(const bf16x8*)(tqB + i * 16 * 64 + h * 32);

    const short* pA = pT + ((size_t)b * Mp + w * 16 + lo) * 64 + quad * 8;
    const short* gB = gT + ((size_t)b * 64 + w * 16 + lo) * Mp + quad * 8;

    bf16x8 pa0 = *(const bf16x8*)(pA);
    bf16x8 pa1 = *(const bf16x8*)(pA + 32);
    bf16x8 gb0 = *(const bf16x8*)(gB);
    bf16x8 gb1 = *(const bf16x8*)(gB + 32);

    f32x4 accO[2];
    accO[0] = f32x4{0.f, 0.f, 0.f, 0.f};
    accO[1] = f32x4{0.f, 0.f, 0.f, 0.f};
    float m_run[2] = {-1e30f, -1e30f}, l_run[2] = {0.f, 0.f};

    int nch = Mp >> 6;
    for (int ch = 0; ch < nch; ++ch) {
        int m0 = ch << 6;
        bf16x8 pa0n, pa1n, gb0n, gb1n;
        bool more = (ch + 1 < nch);
        if (more) {
            int mn = m0 + 64;
            pa0n = *(const bf16x8*)(pA + (size_t)mn * 64);
            pa1n = *(const bf16x8*)(pA + (size_t)mn * 64 + 32);
            gb0n = *(const bf16x8*)(gB + mn);
            gb1n = *(const bf16x8*)(gB + mn + 32);
        }
        // QK: S[i] = m-tile w vs n-tile i
        f32x4 S[2];
        S[0] = f32x4{0.f, 0.f, 0.f, 0.f};
        S[0] = __builtin_amdgcn_mfma_f32_16x16x32_bf16(pa0, bq[0][0], S[0], 0, 0, 0);
        S[0] = __builtin_amdgcn_mfma_f32_16x16x32_bf16(pa1, bq[0][1], S[0], 0, 0, 0);
        S[1] = f32x4{0.f, 0.f, 0.f, 0.f};
        S[1] = __builtin_amdgcn_mfma_f32_16x16x32_bf16(pa0, bq[1][0], S[1], 0, 0, 0);
        S[1] = __builtin_amdgcn_mfma_f32_16x16x32_bf16(pa1, bq[1][1], S[1], 0, 0, 0);
        float cm[2] = {-1e30f, -1e30f};
#pragma unroll
        for (int rg = 0; rg < 4; ++rg) {
            int mglob = m0 + w * 16 + quad * 4 + rg;
            bool oob = mglob >= M;
#pragma unroll
            for (int i = 0; i < 2; ++i) {
                if (oob) S[i][rg] = -1e30f;
                cm[i] = fmaxf(cm[i], S[i][rg]);
            }
        }
#pragma unroll
        for (int i = 0; i < 2; ++i) {
            cm[i] = fmaxf(cm[i], __shfl_xor(cm[i], 16, 64));
            cm[i] = fmaxf(cm[i], __shfl_xor(cm[i], 32, 64));
        }
        if (lane < 16) { s_red[w][lo] = cm[0]; s_red[w][16 + lo] = cm[1]; }
        __syncthreads();   // (A)
        float al[2];
#pragma unroll
        for (int i = 0; i < 2; ++i) {
            int n = i * 16 + lo;
            float chm = fmaxf(fmaxf(s_red[0][n], s_red[1][n]),
                              fmaxf(s_red[2][n], s_red[3][n]));
            float mn_ = fmaxf(m_run[i], chm);
            al[i] = __expf(m_run[i] - mn_);
            m_run[i] = mn_;
            float ps = 0.f;
            short4 pw;
#pragma unroll
            for (int rg = 0; rg < 4; ++rg) {
                float e = __expf(S[i][rg] - mn_);
                ps += e;
                ((short*)&pw)[rg] = f2b(e);
            }
            ps += __shfl_xor(ps, 16, 64);
            ps += __shfl_xor(ps, 32, 64);
            if (lane < 16) s_red2[w][n] = ps;
            *(short4*)&s_P[n][w * 16 + quad * 4] = pw;
        }
        if (w == 0 && lane < 16) { s_alpha[lo] = al[0]; s_alpha[16 + lo] = al[1]; }
        __syncthreads();   // (B)
#pragma unroll
        for (int i = 0; i < 2; ++i) {
            int n = i * 16 + lo;
            l_run[i] = l_run[i] * al[i] +
                       (s_red2[0][n] + s_red2[1][n] + s_red2[2][n] + s_red2[3][n]);
#pragma unroll
            for (int rg = 0; rg < 4; ++rg)
                accO[i][rg] *= s_alpha[i * 16 + quad * 4 + rg];
            const bf16x8 a0 = *(const bf16x8*)&s_P[n][quad * 8];
            const bf16x8 a1 = *(const bf16x8*)&s_P[n][32 + quad * 8];
            accO[i] = __builtin_amdgcn_mfma_f32_16x16x32_bf16(a0, gb0, accO[i], 0, 0, 0);
            accO[i] = __builtin_amdgcn_mfma_f32_16x16x32_bf16(a1, gb1, accO[i], 0, 0, 0);
        }
        if (more) { pa0 = pa0n; pa1 = pa1n; gb0 = gb0n; gb1 = gb1n; }
    }
    if (w == 0 && lane < 16) { s_lf[lo] = l_run[0]; s_lf[16 + lo] = l_run[1]; }
    __syncthreads();
#pragma unroll
    for (int i = 0; i < 2; ++i)
#pragma unroll
        for (int rg = 0; rg < 4; ++rg) {
            int n = i * 16 + quad * 4 + rg;
            outm[((size_t)b * NN + n0 + n) * 64 + w * 16 + lo] = accO[i][rg] / s_lf[n];
        }
}

// ---------------- K4: z[b][q][j*64+l] = sum_cp z_w[q][cp] * outm[b][cp*36+j][l] ----------------
__global__ __launch_bounds__(256) void k_z(const float* __restrict__ outm,
                                           const float* __restrict__ z_w,
                                           float* __restrict__ z) {
    __shared__ float s_u[64][65];
    __shared__ float s_zw[64][65];
    int t = threadIdx.x;
    int blk = blockIdx.x;
    int b = blk / (36 * 4);
    int rem = blk % (36 * 4);
    int j = rem / 4;
    int qc = (rem % 4) * 64;
#pragma unroll
    for (int r = 0; r < 16; ++r) {
        int e = t + r * 256;
        int cl = e >> 6, ll = e & 63;
        s_u[cl][ll] = outm[((size_t)b * NN + cl * 36 + j) * 64 + ll];
        s_zw[cl][ll] = z_w[(qc + cl) * 64 + ll];
    }
    __syncthreads();
    int l = t & 63, qg = t >> 6;
    float acc[16];
#pragma unroll
    for (int i = 0; i < 16; ++i) acc[i] = 0.f;
    for (int cc = 0; cc < 64; ++cc) {
        float uv = s_u[cc][l];
#pragma unroll
        for (int qq = 0; qq < 16; ++qq)
            acc[qq] += s_zw[qg * 16 + qq][cc] * uv;
    }
#pragma unroll
    for (int qq = 0; qq < 16; ++qq)
        z[((size_t)b * CPc + qc + qg * 16 + qq) * NN + j * 64 + l] = acc[qq];
}

// ---------------- K5: per-channel sum / sumsq ----------------
__global__ __launch_bounds__(256) void k_stats(const float* __restrict__ z,
                                               float* __restrict__ stats) {
    int q = blockIdx.x;
    int t = threadIdx.x;
    float s = 0.f, s2 = 0.f;
    for (int i = t; i < BB * NN; i += 256) {
        int b = i / NN, sp = i % NN;
        float v = z[((size_t)b * CPc + q) * NN + sp];
        s += v; s2 += v * v;
    }
    for (int o = 32; o >= 1; o >>= 1) {
        s += __shfl_down(s, o, 64);
        s2 += __shfl_down(s2, o, 64);
    }
    __shared__ float sh[2][4];
    int w = t >> 6, lane = t & 63;
    if (lane == 0) { sh[0][w] = s; sh[1][w] = s2; }
    __syncthreads();
    if (t == 0) {
        stats[q * 2]     = sh[0][0] + sh[0][1] + sh[0][2] + sh[0][3];
        stats[q * 2 + 1] = sh[1][0] + sh[1][1] + sh[1][2] + sh[1][3];
    }
}

// ---------------- K6: BN normalize + accumulate ----------------
__global__ __launch_bounds__(256) void k_norm(const float* __restrict__ z,
                                              const float* __restrict__ stats,
                                              const float* __restrict__ gamma,
                                              const float* __restrict__ beta,
                                              float* __restrict__ acc,
                                              float* __restrict__ outp,
                                              int mode) {
    int idx = blockIdx.x * 256 + threadIdx.x;
    if (idx >= BB * CPc * NN) return;
    int q = (idx / NN) & 255;
    float inv = 1.f / (float)(BB * NN);
    float mean = stats[q * 2] * inv;
    float var = stats[q * 2 + 1] * inv - mean * mean;
    float r = rsqrtf(var + 1e-5f);
    float v = (z[idx] - mean) * r * gamma[q] + beta[q];
    if (mode == 0)      acc[idx] = v;
    else if (mode == 1) acc[idx] += v;
    else                outp[idx] = acc[idx] + v;
}

extern "C" void kernel_launch(void* const* d_in, const int* in_sizes, int n_in,
                              void* d_out, int out_size, void* d_ws, size_t ws_size,
                              hipStream_t stream) {
    const float* persp = (const float*)d_in[0];
    const float* resp[5];
    for (int i = 0; i < 5; ++i) resp[i] = (const float*)d_in[1 + i];
    const float* t_w = (const float*)d_in[6];
    const float* z_w = (const float*)d_in[7];
    const float *p_w[5], *g_w[5], *bng[5], *bnb[5];
    for (int i = 0; i < 5; ++i) {
        p_w[i] = (const float*)d_in[8 + 4 * i];
        g_w[i] = (const float*)d_in[9 + 4 * i];
        bng[i] = (const float*)d_in[10 + 4 * i];
        bnb[i] = (const float*)d_in[11 + 4 * i];
    }
    float* ws = (float*)d_ws;
    short* TQb = (short*)ws;            // 589824 shorts
    short* PTb = TQb + 589824;          // B*2304*64 max (bf16)
    short* GTb = PTb + 589824;
    float* OUT = ws + 884736;           // 589824 fp32
    float* Z   = OUT + 589824;          // 2359296
    float* ACC = Z + 2359296;           // 2359296
    float* STATS = ACC + 2359296;       // 512
    float* PPART = STATS + 512;         // 73728 max
    float* GPART = PPART + 73728;       // 73728 max

    const int Ms[5]  = {2304, 2304, 576, 144, 36};
    const int Mps[5] = {2304, 2304, 576, 192, 64};
    const int Crs[5] = {64, 256, 512, 1024, 2048};
    const int Ss[5]  = {1, 1, 1, 2, 8};

    k_tq<<<BB * (NN / 4), 256, 0, stream>>>(persp, t_w, TQb);
    for (int i = 0; i < 5; ++i) {
        int M = Ms[i], Mp = Mps[i], Cr = Crs[i], S = Ss[i];
        k_pg<<<BB * (M / 4) * S, 256, 0, stream>>>(resp[i], p_w[i], g_w[i],
                                                   PTb, GTb, PPART, GPART, Cr, M, Mp, S);
        if (S > 1)
            k_conv<<<BB * Mp * 64 / 256, 256, 0, stream>>>(PPART, GPART, PTb, GTb, M, Mp, S);
        k_attn<<<BB * (NN / 32), 256, 0, stream>>>(TQb, PTb, GTb, OUT, M, Mp);
        k_z<<<BB * 36 * 4, 256, 0, stream>>>(OUT, z_w, Z);
        k_stats<<<256, 256, 0, stream>>>(Z, STATS);
        int mode = (i == 0) ? 0 : ((i == 4) ? 2 : 1);
        k_norm<<<BB * CPc * NN / 256, 256, 0, stream>>>(Z, STATS, bng[i], bnb[i], ACC,
                                                        (float*)d_out, mode);
    }
}

// Round 5
// 493.405 us; speedup vs baseline: 3.6141x; 1.2070x over previous
//
#include <hip/hip_runtime.h>
#include <hip/hip_bf16.h>
#include <string.h>

#define BB 4
#define CPc 256
#define NN 2304   // 48*48

typedef __attribute__((ext_vector_type(8))) short bf16x8;
typedef __attribute__((ext_vector_type(4))) float f32x4;

__device__ __forceinline__ short f2b(float x) {
    __hip_bfloat16 h = __float2bfloat16(x);
    return *reinterpret_cast<short*>(&h);
}
__device__ __forceinline__ float b2f16(short v) {
    union { float f; unsigned u; } x;
    x.u = ((unsigned)(unsigned short)v) << 16;
    return x.f;
}

// ---------------- K0: convert weights fp32 -> bf16 ----------------
// TWb: 64x256 (t_w); WPb/WGb: concat of 64xCr_i, Cr={64,256,512,1024,2048}
// grid = 2016 blocks x 256 = 516096 = 16384 + 2*249856 exactly
__global__ __launch_bounds__(256) void k_wcvt(
    const float* __restrict__ t_w,
    const float* p0, const float* p1, const float* p2, const float* p3, const float* p4,
    const float* g0, const float* g1, const float* g2, const float* g3, const float* g4,
    short* __restrict__ TWb, short* __restrict__ WPb, short* __restrict__ WGb) {
    int idx = blockIdx.x * 256 + threadIdx.x;
    if (idx < 16384) { TWb[idx] = f2b(t_w[idx]); return; }
    int k = idx - 16384;
    bool isP = k < 249856;
    if (!isP) k -= 249856;
    int i, off;
    if (k < 4096)        { i = 0; off = 0; }
    else if (k < 20480)  { i = 1; off = 4096; }
    else if (k < 53248)  { i = 2; off = 20480; }
    else if (k < 118784) { i = 3; off = 53248; }
    else                 { i = 4; off = 118784; }
    const float* s;
    if (isP) s = (i == 0) ? p0 : (i == 1) ? p1 : (i == 2) ? p2 : (i == 3) ? p3 : p4;
    else     s = (i == 0) ? g0 : (i == 1) ? g1 : (i == 2) ? g2 : (i == 3) ? g3 : g4;
    (isP ? WPb : WGb)[k] = f2b(s[k - off]);
}

// ---------------- K1: batched MFMA 1x1 convs ----------------
// seg 0: tq[b][n][c] = persp-conv with t_w  (no g output)
// seg 1..5: pT_i[b][m][c], gTt_i[b][c][m] from resp_i
// frag_r (resp columns) is A for p-output and B for g-output.
// grid = 484 blocks (cum {144,288,432,468,480,484}), block = 256
__global__ __launch_bounds__(256) void k_conv(
    const float* __restrict__ persp,
    const float* r0, const float* r1, const float* r2, const float* r3, const float* r4,
    const short* __restrict__ TWb, const short* __restrict__ WPb, const short* __restrict__ WGb,
    short* __restrict__ TQb, short* __restrict__ PTb, short* __restrict__ GTb) {
    const int CUM[7]  = {0, 144, 288, 432, 468, 480, 484};
    const int CRs[6]  = {256, 64, 256, 512, 1024, 2048};
    const int Mus[6]  = {2304, 2304, 2304, 576, 144, 36};
    const int Mps[6]  = {2304, 2304, 2304, 576, 192, 64};
    const int WOFF[6] = {0, 0, 4096, 20480, 53248, 118784};
    const int POFF[6] = {0, 0, 589824, 1179648, 1327104, 1376256};

    int blk = blockIdx.x, t = threadIdx.x;
    int w = t >> 6, lane = t & 63, lo = lane & 15, quad = lane >> 4;
    int seg = 0;
#pragma unroll
    for (int s_ = 1; s_ <= 5; ++s_) if (blk >= CUM[s_]) seg = s_;
    int Cr = CRs[seg], M = Mus[seg], Mp = Mps[seg];
    const float* in = (seg == 0) ? persp : (seg == 1) ? r0 : (seg == 2) ? r1 :
                      (seg == 3) ? r2 : (seg == 4) ? r3 : r4;
    const short* wp = (seg == 0) ? TWb : WPb + WOFF[seg];
    const short* wg = WGb + WOFF[seg];
    short* outP = (seg == 0) ? TQb : PTb + POFF[seg];
    short* outG = GTb + POFF[seg];
    bool has_g = (seg != 0);
    int local = blk - CUM[seg];
    int mb = Mp >> 6;
    int b = local / mb, m0 = (local % mb) * 64;

    int mA = m0 + w * 16 + lo;
    int mA_c = mA < M ? mA : M - 1;            // clamp: garbage rows masked downstream
    const float* colBase = in + (size_t)b * Cr * M + mA_c;

    f32x4 accP[4], accG[4];
#pragma unroll
    for (int ct = 0; ct < 4; ++ct) {
        accP[ct] = f32x4{0.f, 0.f, 0.f, 0.f};
        accG[ct] = f32x4{0.f, 0.f, 0.f, 0.f};
    }

    for (int kc = 0; kc < Cr; kc += 32) {
        float v[8];
#pragma unroll
        for (int j = 0; j < 8; ++j)
            v[j] = colBase[(size_t)(kc + quad * 8 + j) * M];
        bf16x8 fr;
#pragma unroll
        for (int j = 0; j < 8; ++j) ((short*)&fr)[j] = f2b(v[j]);
#pragma unroll
        for (int ct = 0; ct < 4; ++ct) {
            const bf16x8 fp = *(const bf16x8*)&wp[(size_t)(ct * 16 + lo) * Cr + kc + quad * 8];
            accP[ct] = __builtin_amdgcn_mfma_f32_16x16x32_bf16(fr, fp, accP[ct], 0, 0, 0);
            if (has_g) {
                const bf16x8 fg = *(const bf16x8*)&wg[(size_t)(ct * 16 + lo) * Cr + kc + quad * 8];
                accG[ct] = __builtin_amdgcn_mfma_f32_16x16x32_bf16(fg, fr, accG[ct], 0, 0, 0);
            }
        }
    }
    // p/tq epilogue: D[m][c], col=lo=c, row=quad*4+rg=m
    int mP = m0 + w * 16 + quad * 4;
#pragma unroll
    for (int ct = 0; ct < 4; ++ct) {
        int c = ct * 16 + lo;
#pragma unroll
        for (int rg = 0; rg < 4; ++rg)
            outP[((size_t)b * Mp + mP + rg) * 64 + c] = f2b(accP[ct][rg]);
    }
    if (has_g) {
        // g epilogue: D[c][m], col=lo=m, row=quad*4+rg within ct*16
        int mG = m0 + w * 16 + lo;
#pragma unroll
        for (int ct = 0; ct < 4; ++ct) {
            int cG = ct * 16 + quad * 4;
#pragma unroll
            for (int rg = 0; rg < 4; ++rg)
                outG[((size_t)b * 64 + cG + rg) * Mp + mG] = f2b(accG[ct][rg]);
        }
    }
}

// ---------------- K2: batched MFMA flash attention (all 5 iters) ----------------
// grid = 5 * 288 = 1440, block = 256
__global__ __launch_bounds__(256) void k_attn(const short* __restrict__ tq,
                                              const short* __restrict__ PTb,
                                              const short* __restrict__ GTb,
                                              float* __restrict__ OUT) {
    const int AM[5]   = {2304, 2304, 576, 144, 36};
    const int AMp[5]  = {2304, 2304, 576, 192, 64};
    const int APOFF[5] = {0, 589824, 1179648, 1327104, 1376256};

    __shared__ __align__(16) short s_P[32][72];
    __shared__ float s_red[4][32];
    __shared__ float s_red2[4][32];
    __shared__ float s_alpha[32];
    __shared__ float s_lf[32];

    int t = threadIdx.x;
    int seg = blockIdx.x / 288;
    int r = blockIdx.x % 288;
    int b = r / 72;
    int n0 = (r % 72) * 32;
    int M = AM[seg], Mp = AMp[seg];
    const short* pT = PTb + APOFF[seg];
    const short* gT = GTb + APOFF[seg];
    float* outm = OUT + (size_t)seg * 589824;

    int w = t >> 6, lane = t & 63, lo = lane & 15, quad = lane >> 4;

    const short* tqB = tq + ((size_t)b * NN + n0 + lo) * 64 + quad * 8;
    bf16x8 bq[2][2];
#pragma unroll
    for (int i = 0; i < 2; ++i)
#pragma unroll
        for (int h = 0; h < 2; ++h)
            bq[i][h] = *(const bf16x8*)(tqB + i * 16 * 64 + h * 32);

    const short* pA = pT + ((size_t)b * Mp + w * 16 + lo) * 64 + quad * 8;
    const short* gB = gT + ((size_t)b * 64 + w * 16 + lo) * Mp + quad * 8;

    bf16x8 pa0 = *(const bf16x8*)(pA);
    bf16x8 pa1 = *(const bf16x8*)(pA + 32);
    bf16x8 gb0 = *(const bf16x8*)(gB);
    bf16x8 gb1 = *(const bf16x8*)(gB + 32);

    f32x4 accO[2];
    accO[0] = f32x4{0.f, 0.f, 0.f, 0.f};
    accO[1] = f32x4{0.f, 0.f, 0.f, 0.f};
    float m_run[2] = {-1e30f, -1e30f}, l_run[2] = {0.f, 0.f};

    int nch = Mp >> 6;
    for (int ch = 0; ch < nch; ++ch) {
        int m0 = ch << 6;
        bf16x8 pa0n, pa1n, gb0n, gb1n;
        bool more = (ch + 1 < nch);
        if (more) {
            int mn = m0 + 64;
            pa0n = *(const bf16x8*)(pA + (size_t)mn * 64);
            pa1n = *(const bf16x8*)(pA + (size_t)mn * 64 + 32);
            gb0n = *(const bf16x8*)(gB + mn);
            gb1n = *(const bf16x8*)(gB + mn + 32);
        }
        f32x4 S[2];
        S[0] = f32x4{0.f, 0.f, 0.f, 0.f};
        S[0] = __builtin_amdgcn_mfma_f32_16x16x32_bf16(pa0, bq[0][0], S[0], 0, 0, 0);
        S[0] = __builtin_amdgcn_mfma_f32_16x16x32_bf16(pa1, bq[0][1], S[0], 0, 0, 0);
        S[1] = f32x4{0.f, 0.f, 0.f, 0.f};
        S[1] = __builtin_amdgcn_mfma_f32_16x16x32_bf16(pa0, bq[1][0], S[1], 0, 0, 0);
        S[1] = __builtin_amdgcn_mfma_f32_16x16x32_bf16(pa1, bq[1][1], S[1], 0, 0, 0);
        float cm[2] = {-1e30f, -1e30f};
#pragma unroll
        for (int rg = 0; rg < 4; ++rg) {
            int mglob = m0 + w * 16 + quad * 4 + rg;
            bool oob = mglob >= M;
#pragma unroll
            for (int i = 0; i < 2; ++i) {
                if (oob) S[i][rg] = -1e30f;
                cm[i] = fmaxf(cm[i], S[i][rg]);
            }
        }
#pragma unroll
        for (int i = 0; i < 2; ++i) {
            cm[i] = fmaxf(cm[i], __shfl_xor(cm[i], 16, 64));
            cm[i] = fmaxf(cm[i], __shfl_xor(cm[i], 32, 64));
        }
        if (lane < 16) { s_red[w][lo] = cm[0]; s_red[w][16 + lo] = cm[1]; }
        __syncthreads();
        float al[2];
#pragma unroll
        for (int i = 0; i < 2; ++i) {
            int n = i * 16 + lo;
            float chm = fmaxf(fmaxf(s_red[0][n], s_red[1][n]),
                              fmaxf(s_red[2][n], s_red[3][n]));
            float mn_ = fmaxf(m_run[i], chm);
            al[i] = __expf(m_run[i] - mn_);
            m_run[i] = mn_;
            float ps = 0.f;
            short4 pw;
#pragma unroll
            for (int rg = 0; rg < 4; ++rg) {
                float e = __expf(S[i][rg] - mn_);
                ps += e;
                ((short*)&pw)[rg] = f2b(e);
            }
            ps += __shfl_xor(ps, 16, 64);
            ps += __shfl_xor(ps, 32, 64);
            if (lane < 16) s_red2[w][n] = ps;
            *(short4*)&s_P[n][w * 16 + quad * 4] = pw;
        }
        if (w == 0 && lane < 16) { s_alpha[lo] = al[0]; s_alpha[16 + lo] = al[1]; }
        __syncthreads();
#pragma unroll
        for (int i = 0; i < 2; ++i) {
            int n = i * 16 + lo;
            l_run[i] = l_run[i] * al[i] +
                       (s_red2[0][n] + s_red2[1][n] + s_red2[2][n] + s_red2[3][n]);
#pragma unroll
            for (int rg = 0; rg < 4; ++rg)
                accO[i][rg] *= s_alpha[i * 16 + quad * 4 + rg];
            const bf16x8 a0 = *(const bf16x8*)&s_P[n][quad * 8];
            const bf16x8 a1 = *(const bf16x8*)&s_P[n][32 + quad * 8];
            accO[i] = __builtin_amdgcn_mfma_f32_16x16x32_bf16(a0, gb0, accO[i], 0, 0, 0);
            accO[i] = __builtin_amdgcn_mfma_f32_16x16x32_bf16(a1, gb1, accO[i], 0, 0, 0);
        }
        if (more) { pa0 = pa0n; pa1 = pa1n; gb0 = gb0n; gb1 = gb1n; }
    }
    if (w == 0 && lane < 16) { s_lf[lo] = l_run[0]; s_lf[16 + lo] = l_run[1]; }
    __syncthreads();
#pragma unroll
    for (int i = 0; i < 2; ++i)
#pragma unroll
        for (int rg = 0; rg < 4; ++rg) {
            int n = i * 16 + quad * 4 + rg;
            outm[((size_t)b * NN + n0 + n) * 64 + w * 16 + lo] = accO[i][rg] / s_lf[n];
        }
}

// ---------------- K3: batched z-conv (wrong-reshape folded) + fused BN stats ----------------
// z_i[b][q][j*64+l] = sum_cp z_w[q][cp] * outm_i[b][cp*36+j][l]; Z stored bf16
// grid = 5 * 576, block = 256
__global__ __launch_bounds__(256) void k_z(const float* __restrict__ OUT,
                                           const float* __restrict__ z_w,
                                           short* __restrict__ Zb,
                                           float* __restrict__ STATS) {
    __shared__ float s_u[64][65];
    __shared__ float s_zw[64][65];
    int t = threadIdx.x;
    int seg = blockIdx.x / 576;
    int r = blockIdx.x % 576;
    int b = r / 144;
    int rem = r % 144;
    int j = rem / 4;
    int qc = (rem % 4) * 64;
    const float* outm = OUT + (size_t)seg * 589824;
    short* z = Zb + (size_t)seg * 2359296;
    float* stats = STATS + seg * 512;
#pragma unroll
    for (int rr = 0; rr < 16; ++rr) {
        int e = t + rr * 256;
        int cl = e >> 6, ll = e & 63;
        s_u[cl][ll] = outm[((size_t)b * NN + cl * 36 + j) * 64 + ll];
        s_zw[cl][ll] = z_w[(qc + cl) * 64 + ll];
    }
    __syncthreads();
    int l = t & 63, qg = t >> 6;
    float acc[16];
#pragma unroll
    for (int i = 0; i < 16; ++i) acc[i] = 0.f;
    for (int cc = 0; cc < 64; ++cc) {
        float uv = s_u[cc][l];
#pragma unroll
        for (int qq = 0; qq < 16; ++qq)
            acc[qq] += s_zw[qg * 16 + qq][cc] * uv;
    }
#pragma unroll
    for (int qq = 0; qq < 16; ++qq) {
        int q = qc + qg * 16 + qq;
        z[((size_t)b * CPc + q) * NN + j * 64 + l] = f2b(acc[qq]);
        float s = acc[qq], s2 = acc[qq] * acc[qq];
        for (int o = 32; o >= 1; o >>= 1) {
            s += __shfl_xor(s, o, 64);
            s2 += __shfl_xor(s2, o, 64);
        }
        if (l == 0) {
            atomicAdd(&stats[q * 2], s);
            atomicAdd(&stats[q * 2 + 1], s2);
        }
    }
}

// ---------------- K4: final BN-normalize-and-sum over 5 iterations ----------------
// grid = 9216 x 256 = 2359296 exactly
__global__ __launch_bounds__(256) void k_final(
    const short* __restrict__ Zb, const float* __restrict__ STATS,
    const float* g0, const float* g1, const float* g2, const float* g3, const float* g4,
    const float* b0, const float* b1, const float* b2, const float* b3, const float* b4,
    float* __restrict__ outp) {
    int idx = blockIdx.x * 256 + threadIdx.x;
    int q = (idx / NN) & 255;
    const float inv = 1.f / (float)(BB * NN);
    float o = 0.f;
#pragma unroll
    for (int i = 0; i < 5; ++i) {
        float mean = STATS[i * 512 + q * 2] * inv;
        float var = STATS[i * 512 + q * 2 + 1] * inv - mean * mean;
        float rr = rsqrtf(var + 1e-5f);
        float zv = b2f16(Zb[(size_t)i * 2359296 + idx]);
        const float* gm = (i == 0) ? g0 : (i == 1) ? g1 : (i == 2) ? g2 : (i == 3) ? g3 : g4;
        const float* bt = (i == 0) ? b0 : (i == 1) ? b1 : (i == 2) ? b2 : (i == 3) ? b3 : b4;
        o += (zv - mean) * rr * gm[q] + bt[q];
    }
    outp[idx] = o;
}

extern "C" void kernel_launch(void* const* d_in, const int* in_sizes, int n_in,
                              void* d_out, int out_size, void* d_ws, size_t ws_size,
                              hipStream_t stream) {
    const float* persp = (const float*)d_in[0];
    const float* resp[5];
    for (int i = 0; i < 5; ++i) resp[i] = (const float*)d_in[1 + i];
    const float* t_w = (const float*)d_in[6];
    const float* z_w = (const float*)d_in[7];
    const float *p_w[5], *g_w[5], *bng[5], *bnb[5];
    for (int i = 0; i < 5; ++i) {
        p_w[i] = (const float*)d_in[8 + 4 * i];
        g_w[i] = (const float*)d_in[9 + 4 * i];
        bng[i] = (const float*)d_in[10 + 4 * i];
        bnb[i] = (const float*)d_in[11 + 4 * i];
    }
    // workspace layout (shorts first, then floats)
    short* TQb = (short*)d_ws;              // 589824
    short* TWb = TQb + 589824;              // 16384
    short* WPb = TWb + 16384;               // 249856
    short* WGb = WPb + 249856;              // 249856
    short* PTb = WGb + 249856;              // 1392640 (= 256 * 5440)
    short* GTb = PTb + 1392640;             // 1392640
    short* Zb  = GTb + 1392640;             // 5 * 2359296 = 11796480
    float* OUT   = (float*)d_ws + 7843840;  // 5 * 589824 = 2949120
    float* STATS = OUT + 2949120;           // 2560

    hipMemsetAsync(STATS, 0, 2560 * sizeof(float), stream);
    k_wcvt<<<2016, 256, 0, stream>>>(t_w,
        p_w[0], p_w[1], p_w[2], p_w[3], p_w[4],
        g_w[0], g_w[1], g_w[2], g_w[3], g_w[4],
        TWb, WPb, WGb);
    k_conv<<<484, 256, 0, stream>>>(persp,
        resp[0], resp[1], resp[2], resp[3], resp[4],
        TWb, WPb, WGb, TQb, PTb, GTb);
    k_attn<<<1440, 256, 0, stream>>>(TQb, PTb, GTb, OUT);
    k_z<<<2880, 256, 0, stream>>>(OUT, z_w, Zb, STATS);
    k_final<<<9216, 256, 0, stream>>>(Zb, STATS,
        bng[0], bng[1], bng[2], bng[3], bng[4],
        bnb[0], bnb[1], bnb[2], bnb[3], bnb[4],
        (float*)d_out);
}

// Round 6
// 381.647 us; speedup vs baseline: 4.6725x; 1.2928x over previous
//
#include <hip/hip_runtime.h>
#include <hip/hip_bf16.h>
#include <string.h>

#define BB 4
#define CPc 256
#define NN 2304   // 48*48

typedef __attribute__((ext_vector_type(8))) short bf16x8;
typedef __attribute__((ext_vector_type(4))) float f32x4;

__device__ __forceinline__ short f2b(float x) {
    __hip_bfloat16 h = __float2bfloat16(x);
    return *reinterpret_cast<short*>(&h);
}
__device__ __forceinline__ float b2f16(short v) {
    union { float f; unsigned u; } x;
    x.u = ((unsigned)(unsigned short)v) << 16;
    return x.f;
}

// ---------------- K0: convert weights fp32 -> bf16 ----------------
// TWb 16384 | ZWb 16384 | WPb/WGb concat of 64xCr_i, Cr={64,256,512,1024,2048}
// total = 32768 + 2*249856 = 532480 -> grid 2080
__global__ __launch_bounds__(256) void k_wcvt(
    const float* __restrict__ t_w, const float* __restrict__ z_w,
    const float* p0, const float* p1, const float* p2, const float* p3, const float* p4,
    const float* g0, const float* g1, const float* g2, const float* g3, const float* g4,
    short* __restrict__ TWb, short* __restrict__ ZWb,
    short* __restrict__ WPb, short* __restrict__ WGb) {
    int idx = blockIdx.x * 256 + threadIdx.x;
    if (idx < 16384) { TWb[idx] = f2b(t_w[idx]); return; }
    if (idx < 32768) { ZWb[idx - 16384] = f2b(z_w[idx - 16384]); return; }
    int k = idx - 32768;
    bool isP = k < 249856;
    if (!isP) k -= 249856;
    int i, off;
    if (k < 4096)        { i = 0; off = 0; }
    else if (k < 20480)  { i = 1; off = 4096; }
    else if (k < 53248)  { i = 2; off = 20480; }
    else if (k < 118784) { i = 3; off = 53248; }
    else                 { i = 4; off = 118784; }
    const float* s;
    if (isP) s = (i == 0) ? p0 : (i == 1) ? p1 : (i == 2) ? p2 : (i == 3) ? p3 : p4;
    else     s = (i == 0) ? g0 : (i == 1) ? g1 : (i == 2) ? g2 : (i == 3) ? g3 : g4;
    (isP ? WPb : WGb)[k] = f2b(s[k - off]);
}

// ---------------- K1: batched MFMA 1x1 convs ----------------
// seg 0: tq[b][n][c]; seg 1..5: pT_i[b][m][c], gTt_i[b][c][m]
// grid = 484 blocks (cum {144,288,432,468,480,484}), block = 256
__global__ __launch_bounds__(256) void k_conv(
    const float* __restrict__ persp,
    const float* r0, const float* r1, const float* r2, const float* r3, const float* r4,
    const short* __restrict__ TWb, const short* __restrict__ WPb, const short* __restrict__ WGb,
    short* __restrict__ TQb, short* __restrict__ PTb, short* __restrict__ GTb) {
    const int CUM[7]  = {0, 144, 288, 432, 468, 480, 484};
    const int CRs[6]  = {256, 64, 256, 512, 1024, 2048};
    const int Mus[6]  = {2304, 2304, 2304, 576, 144, 36};
    const int Mps[6]  = {2304, 2304, 2304, 576, 192, 64};
    const int WOFF[6] = {0, 0, 4096, 20480, 53248, 118784};
    const int POFF[6] = {0, 0, 589824, 1179648, 1327104, 1376256};

    int blk = blockIdx.x, t = threadIdx.x;
    int w = t >> 6, lane = t & 63, lo = lane & 15, quad = lane >> 4;
    int seg = 0;
#pragma unroll
    for (int s_ = 1; s_ <= 5; ++s_) if (blk >= CUM[s_]) seg = s_;
    int Cr = CRs[seg], M = Mus[seg], Mp = Mps[seg];
    const float* in = (seg == 0) ? persp : (seg == 1) ? r0 : (seg == 2) ? r1 :
                      (seg == 3) ? r2 : (seg == 4) ? r3 : r4;
    const short* wp = (seg == 0) ? TWb : WPb + WOFF[seg];
    const short* wg = WGb + WOFF[seg];
    short* outP = (seg == 0) ? TQb : PTb + POFF[seg];
    short* outG = GTb + POFF[seg];
    bool has_g = (seg != 0);
    int local = blk - CUM[seg];
    int mb = Mp >> 6;
    int b = local / mb, m0 = (local % mb) * 64;

    int mA = m0 + w * 16 + lo;
    int mA_c = mA < M ? mA : M - 1;            // clamp: garbage rows masked downstream
    const float* colBase = in + (size_t)b * Cr * M + mA_c;

    f32x4 accP[4], accG[4];
#pragma unroll
    for (int ct = 0; ct < 4; ++ct) {
        accP[ct] = f32x4{0.f, 0.f, 0.f, 0.f};
        accG[ct] = f32x4{0.f, 0.f, 0.f, 0.f};
    }

    for (int kc = 0; kc < Cr; kc += 32) {
        float v[8];
#pragma unroll
        for (int j = 0; j < 8; ++j)
            v[j] = colBase[(size_t)(kc + quad * 8 + j) * M];
        bf16x8 fr;
#pragma unroll
        for (int j = 0; j < 8; ++j) ((short*)&fr)[j] = f2b(v[j]);
#pragma unroll
        for (int ct = 0; ct < 4; ++ct) {
            const bf16x8 fp = *(const bf16x8*)&wp[(size_t)(ct * 16 + lo) * Cr + kc + quad * 8];
            accP[ct] = __builtin_amdgcn_mfma_f32_16x16x32_bf16(fr, fp, accP[ct], 0, 0, 0);
            if (has_g) {
                const bf16x8 fg = *(const bf16x8*)&wg[(size_t)(ct * 16 + lo) * Cr + kc + quad * 8];
                accG[ct] = __builtin_amdgcn_mfma_f32_16x16x32_bf16(fg, fr, accG[ct], 0, 0, 0);
            }
        }
    }
    int mP = m0 + w * 16 + quad * 4;
#pragma unroll
    for (int ct = 0; ct < 4; ++ct) {
        int c = ct * 16 + lo;
#pragma unroll
        for (int rg = 0; rg < 4; ++rg)
            outP[((size_t)b * Mp + mP + rg) * 64 + c] = f2b(accP[ct][rg]);
    }
    if (has_g) {
        int mG = m0 + w * 16 + lo;
#pragma unroll
        for (int ct = 0; ct < 4; ++ct) {
            int cG = ct * 16 + quad * 4;
#pragma unroll
            for (int rg = 0; rg < 4; ++rg)
                outG[((size_t)b * 64 + cG + rg) * Mp + mG] = f2b(accG[ct][rg]);
        }
    }
}

// ---------------- K2: batched MFMA flash attention (all 5 iters) ----------------
// grid = 5 * 288 = 1440, block = 256
__global__ __launch_bounds__(256) void k_attn(const short* __restrict__ tq,
                                              const short* __restrict__ PTb,
                                              const short* __restrict__ GTb,
                                              float* __restrict__ OUT) {
    const int AM[5]   = {2304, 2304, 576, 144, 36};
    const int AMp[5]  = {2304, 2304, 576, 192, 64};
    const int APOFF[5] = {0, 589824, 1179648, 1327104, 1376256};

    __shared__ __align__(16) short s_P[32][72];
    __shared__ float s_red[4][32];
    __shared__ float s_red2[4][32];
    __shared__ float s_alpha[32];
    __shared__ float s_lf[32];

    int t = threadIdx.x;
    int seg = blockIdx.x / 288;
    int r = blockIdx.x % 288;
    int b = r / 72;
    int n0 = (r % 72) * 32;
    int M = AM[seg], Mp = AMp[seg];
    const short* pT = PTb + APOFF[seg];
    const short* gT = GTb + APOFF[seg];
    float* outm = OUT + (size_t)seg * 589824;

    int w = t >> 6, lane = t & 63, lo = lane & 15, quad = lane >> 4;

    const short* tqB = tq + ((size_t)b * NN + n0 + lo) * 64 + quad * 8;
    bf16x8 bq[2][2];
#pragma unroll
    for (int i = 0; i < 2; ++i)
#pragma unroll
        for (int h = 0; h < 2; ++h)
            bq[i][h] = *(const bf16x8*)(tqB + i * 16 * 64 + h * 32);

    const short* pA = pT + ((size_t)b * Mp + w * 16 + lo) * 64 + quad * 8;
    const short* gB = gT + ((size_t)b * 64 + w * 16 + lo) * Mp + quad * 8;

    bf16x8 pa0 = *(const bf16x8*)(pA);
    bf16x8 pa1 = *(const bf16x8*)(pA + 32);
    bf16x8 gb0 = *(const bf16x8*)(gB);
    bf16x8 gb1 = *(const bf16x8*)(gB + 32);

    f32x4 accO[2];
    accO[0] = f32x4{0.f, 0.f, 0.f, 0.f};
    accO[1] = f32x4{0.f, 0.f, 0.f, 0.f};
    float m_run[2] = {-1e30f, -1e30f}, l_run[2] = {0.f, 0.f};

    int nch = Mp >> 6;
    for (int ch = 0; ch < nch; ++ch) {
        int m0 = ch << 6;
        bf16x8 pa0n, pa1n, gb0n, gb1n;
        bool more = (ch + 1 < nch);
        if (more) {
            int mn = m0 + 64;
            pa0n = *(const bf16x8*)(pA + (size_t)mn * 64);
            pa1n = *(const bf16x8*)(pA + (size_t)mn * 64 + 32);
            gb0n = *(const bf16x8*)(gB + mn);
            gb1n = *(const bf16x8*)(gB + mn + 32);
        }
        f32x4 S[2];
        S[0] = f32x4{0.f, 0.f, 0.f, 0.f};
        S[0] = __builtin_amdgcn_mfma_f32_16x16x32_bf16(pa0, bq[0][0], S[0], 0, 0, 0);
        S[0] = __builtin_amdgcn_mfma_f32_16x16x32_bf16(pa1, bq[0][1], S[0], 0, 0, 0);
        S[1] = f32x4{0.f, 0.f, 0.f, 0.f};
        S[1] = __builtin_amdgcn_mfma_f32_16x16x32_bf16(pa0, bq[1][0], S[1], 0, 0, 0);
        S[1] = __builtin_amdgcn_mfma_f32_16x16x32_bf16(pa1, bq[1][1], S[1], 0, 0, 0);
        float cm[2] = {-1e30f, -1e30f};
#pragma unroll
        for (int rg = 0; rg < 4; ++rg) {
            int mglob = m0 + w * 16 + quad * 4 + rg;
            bool oob = mglob >= M;
#pragma unroll
            for (int i = 0; i < 2; ++i) {
                if (oob) S[i][rg] = -1e30f;
                cm[i] = fmaxf(cm[i], S[i][rg]);
            }
        }
#pragma unroll
        for (int i = 0; i < 2; ++i) {
            cm[i] = fmaxf(cm[i], __shfl_xor(cm[i], 16, 64));
            cm[i] = fmaxf(cm[i], __shfl_xor(cm[i], 32, 64));
        }
        if (lane < 16) { s_red[w][lo] = cm[0]; s_red[w][16 + lo] = cm[1]; }
        __syncthreads();
        float al[2];
#pragma unroll
        for (int i = 0; i < 2; ++i) {
            int n = i * 16 + lo;
            float chm = fmaxf(fmaxf(s_red[0][n], s_red[1][n]),
                              fmaxf(s_red[2][n], s_red[3][n]));
            float mn_ = fmaxf(m_run[i], chm);
            al[i] = __expf(m_run[i] - mn_);
            m_run[i] = mn_;
            float ps = 0.f;
            short4 pw;
#pragma unroll
            for (int rg = 0; rg < 4; ++rg) {
                float e = __expf(S[i][rg] - mn_);
                ps += e;
                ((short*)&pw)[rg] = f2b(e);
            }
            ps += __shfl_xor(ps, 16, 64);
            ps += __shfl_xor(ps, 32, 64);
            if (lane < 16) s_red2[w][n] = ps;
            *(short4*)&s_P[n][w * 16 + quad * 4] = pw;
        }
        if (w == 0 && lane < 16) { s_alpha[lo] = al[0]; s_alpha[16 + lo] = al[1]; }
        __syncthreads();
#pragma unroll
        for (int i = 0; i < 2; ++i) {
            int n = i * 16 + lo;
            l_run[i] = l_run[i] * al[i] +
                       (s_red2[0][n] + s_red2[1][n] + s_red2[2][n] + s_red2[3][n]);
#pragma unroll
            for (int rg = 0; rg < 4; ++rg)
                accO[i][rg] *= s_alpha[i * 16 + quad * 4 + rg];
            const bf16x8 a0 = *(const bf16x8*)&s_P[n][quad * 8];
            const bf16x8 a1 = *(const bf16x8*)&s_P[n][32 + quad * 8];
            accO[i] = __builtin_amdgcn_mfma_f32_16x16x32_bf16(a0, gb0, accO[i], 0, 0, 0);
            accO[i] = __builtin_amdgcn_mfma_f32_16x16x32_bf16(a1, gb1, accO[i], 0, 0, 0);
        }
        if (more) { pa0 = pa0n; pa1 = pa1n; gb0 = gb0n; gb1 = gb1n; }
    }
    if (w == 0 && lane < 16) { s_lf[lo] = l_run[0]; s_lf[16 + lo] = l_run[1]; }
    __syncthreads();
#pragma unroll
    for (int i = 0; i < 2; ++i)
#pragma unroll
        for (int rg = 0; rg < 4; ++rg) {
            int n = i * 16 + quad * 4 + rg;
            outm[((size_t)b * NN + n0 + n) * 64 + w * 16 + lo] = accO[i][rg] / s_lf[n];
        }
}

// ---------------- K3: MFMA z-conv + fused BN stats ----------------
// Key identity: viewing OUT[seg][b] flat, V_b[cp][sp] = flat[cp*2304+sp] (the
// "wrong reshape" is a free reinterpretation). Z_b = z_w(256x64) . V_b(64x2304).
// grid = 5 * 4 * 36 = 720, block = 256. Z stored bf16; stats via atomics.
__global__ __launch_bounds__(256) void k_z(const float* __restrict__ OUT,
                                           const short* __restrict__ ZWb,
                                           short* __restrict__ Zb,
                                           float* __restrict__ STATS) {
    __shared__ __align__(16) short s_ut[64][72];   // V^T tile: [sp][cp] bf16
    int t = threadIdx.x;
    int seg = blockIdx.x / 144;
    int r = blockIdx.x % 144;
    int b = r / 36;
    int sp0 = (r % 36) * 64;
    const float* F = OUT + (size_t)seg * 589824 + (size_t)b * 147456;
    short* z = Zb + (size_t)seg * 2359296 + (size_t)b * 589824;
    float* stats = STATS + seg * 512;

    int w = t >> 6, lane = t & 63, lo = lane & 15, quad = lane >> 4;

    // A-frags: bf16 z_w rows; wave w owns q in [w*64, w*64+64)
    bf16x8 af[4][2];
#pragma unroll
    for (int qt = 0; qt < 4; ++qt)
#pragma unroll
        for (int h = 0; h < 2; ++h)
            af[qt][h] = *(const bf16x8*)&ZWb[(size_t)(w * 64 + qt * 16 + lo) * 64 + h * 32 + quad * 8];

    // stage V^T tile: coalesced dword loads (fixed cp, sp=lane), b64 transposed writes
#pragma unroll
    for (int rr = 0; rr < 4; ++rr) {
        int idx = t + rr * 256;
        int spl = idx & 63;
        int cp0 = (idx >> 6) << 2;
        short4 pk;
        pk.x = f2b(F[(size_t)(cp0 + 0) * 2304 + sp0 + spl]);
        pk.y = f2b(F[(size_t)(cp0 + 1) * 2304 + sp0 + spl]);
        pk.z = f2b(F[(size_t)(cp0 + 2) * 2304 + sp0 + spl]);
        pk.w = f2b(F[(size_t)(cp0 + 3) * 2304 + sp0 + spl]);
        *(short4*)&s_ut[spl][cp0] = pk;
    }
    __syncthreads();

    bf16x8 bfr[4][2];
#pragma unroll
    for (int st = 0; st < 4; ++st)
#pragma unroll
        for (int h = 0; h < 2; ++h)
            bfr[st][h] = *(const bf16x8*)&s_ut[st * 16 + lo][h * 32 + quad * 8];

    f32x4 acc[4][4];
#pragma unroll
    for (int qt = 0; qt < 4; ++qt)
#pragma unroll
        for (int st = 0; st < 4; ++st) {
            acc[qt][st] = f32x4{0.f, 0.f, 0.f, 0.f};
            acc[qt][st] = __builtin_amdgcn_mfma_f32_16x16x32_bf16(af[qt][0], bfr[st][0], acc[qt][st], 0, 0, 0);
            acc[qt][st] = __builtin_amdgcn_mfma_f32_16x16x32_bf16(af[qt][1], bfr[st][1], acc[qt][st], 0, 0, 0);
        }

    // epilogue: store bf16 Z + fused per-channel sum/sumsq
#pragma unroll
    for (int qt = 0; qt < 4; ++qt) {
        float s1[4] = {0.f, 0.f, 0.f, 0.f};
        float s2[4] = {0.f, 0.f, 0.f, 0.f};
        int qb = w * 64 + qt * 16 + quad * 4;
#pragma unroll
        for (int st = 0; st < 4; ++st) {
            int sp = sp0 + st * 16 + lo;
#pragma unroll
            for (int rg = 0; rg < 4; ++rg) {
                float v = acc[qt][st][rg];
                z[(size_t)(qb + rg) * 2304 + sp] = f2b(v);
                s1[rg] += v;
                s2[rg] += v * v;
            }
        }
#pragma unroll
        for (int rg = 0; rg < 4; ++rg) {
            for (int o = 8; o >= 1; o >>= 1) {
                s1[rg] += __shfl_xor(s1[rg], o, 16);
                s2[rg] += __shfl_xor(s2[rg], o, 16);
            }
            if (lo == 0) {
                atomicAdd(&stats[(qb + rg) * 2], s1[rg]);
                atomicAdd(&stats[(qb + rg) * 2 + 1], s2[rg]);
            }
        }
    }
}

// ---------------- K4: final BN-normalize-and-sum over 5 iterations ----------------
// grid = 9216 x 256 = 2359296 exactly
__global__ __launch_bounds__(256) void k_final(
    const short* __restrict__ Zb, const float* __restrict__ STATS,
    const float* g0, const float* g1, const float* g2, const float* g3, const float* g4,
    const float* b0, const float* b1, const float* b2, const float* b3, const float* b4,
    float* __restrict__ outp) {
    int idx = blockIdx.x * 256 + threadIdx.x;
    int q = (idx / NN) & 255;
    const float inv = 1.f / (float)(BB * NN);
    float o = 0.f;
#pragma unroll
    for (int i = 0; i < 5; ++i) {
        float mean = STATS[i * 512 + q * 2] * inv;
        float var = STATS[i * 512 + q * 2 + 1] * inv - mean * mean;
        float rr = rsqrtf(var + 1e-5f);
        float zv = b2f16(Zb[(size_t)i * 2359296 + idx]);
        const float* gm = (i == 0) ? g0 : (i == 1) ? g1 : (i == 2) ? g2 : (i == 3) ? g3 : g4;
        const float* bt = (i == 0) ? b0 : (i == 1) ? b1 : (i == 2) ? b2 : (i == 3) ? b3 : b4;
        o += (zv - mean) * rr * gm[q] + bt[q];
    }
    outp[idx] = o;
}

extern "C" void kernel_launch(void* const* d_in, const int* in_sizes, int n_in,
                              void* d_out, int out_size, void* d_ws, size_t ws_size,
                              hipStream_t stream) {
    const float* persp = (const float*)d_in[0];
    const float* resp[5];
    for (int i = 0; i < 5; ++i) resp[i] = (const float*)d_in[1 + i];
    const float* t_w = (const float*)d_in[6];
    const float* z_w = (const float*)d_in[7];
    const float *p_w[5], *g_w[5], *bng[5], *bnb[5];
    for (int i = 0; i < 5; ++i) {
        p_w[i] = (const float*)d_in[8 + 4 * i];
        g_w[i] = (const float*)d_in[9 + 4 * i];
        bng[i] = (const float*)d_in[10 + 4 * i];
        bnb[i] = (const float*)d_in[11 + 4 * i];
    }
    // workspace layout (shorts first, then floats)
    short* TQb = (short*)d_ws;              // 589824
    short* TWb = TQb + 589824;              // 16384
    short* ZWb = TWb + 16384;               // 16384
    short* WPb = ZWb + 16384;               // 249856
    short* WGb = WPb + 249856;              // 249856
    short* PTb = WGb + 249856;              // 1392640
    short* GTb = PTb + 1392640;             // 1392640
    short* Zb  = GTb + 1392640;             // 5 * 2359296 = 11796480
    float* OUT   = (float*)d_ws + 7852032;  // 5 * 589824 = 2949120 floats
    float* STATS = OUT + 2949120;           // 2560

    hipMemsetAsync(STATS, 0, 2560 * sizeof(float), stream);
    k_wcvt<<<2080, 256, 0, stream>>>(t_w, z_w,
        p_w[0], p_w[1], p_w[2], p_w[3], p_w[4],
        g_w[0], g_w[1], g_w[2], g_w[3], g_w[4],
        TWb, ZWb, WPb, WGb);
    k_conv<<<484, 256, 0, stream>>>(persp,
        resp[0], resp[1], resp[2], resp[3], resp[4],
        TWb, WPb, WGb, TQb, PTb, GTb);
    k_attn<<<1440, 256, 0, stream>>>(TQb, PTb, GTb, OUT);
    k_z<<<720, 256, 0, stream>>>(OUT, ZWb, Zb, STATS);
    k_final<<<9216, 256, 0, stream>>>(Zb, STATS,
        bng[0], bng[1], bng[2], bng[3], bng[4],
        bnb[0], bnb[1], bnb[2], bnb[3], bnb[4],
        (float*)d_out);
}